// Round 4
// baseline (596.391 us; speedup 1.0000x reference)
//
#include <hip/hip_runtime.h>

#define S_ 1024
#define M_ 1024
#define T_ 2048
#define B_ 4
#define H_ 16
#define DM_ 1024
#define DH_ 64

typedef __attribute__((ext_vector_type(8))) short s16x8;
typedef __attribute__((ext_vector_type(16))) float f32x16;

__device__ __forceinline__ unsigned short f2b(float x){
  unsigned int u = __float_as_uint(x);
  u = (u + 0x7fffu + ((u>>16)&1u)) >> 16;
  return (unsigned short)u;
}
__device__ __forceinline__ float b2f(unsigned short h){
  return __uint_as_float(((unsigned int)h)<<16);
}
__device__ __forceinline__ uint4 pack8(const float* v){
  uint4 o;
  o.x = (unsigned)f2b(v[0]) | ((unsigned)f2b(v[1])<<16);
  o.y = (unsigned)f2b(v[2]) | ((unsigned)f2b(v[3])<<16);
  o.z = (unsigned)f2b(v[4]) | ((unsigned)f2b(v[5])<<16);
  o.w = (unsigned)f2b(v[6]) | ((unsigned)f2b(v[7])<<16);
  return o;
}

// ---------------- cast kernels ----------------
__global__ __launch_bounds__(256) void cast_cat(const float* __restrict__ a,
    const float* __restrict__ b, unsigned short* __restrict__ dst, int n8, int na8)
{
  int i = blockIdx.x*256 + threadIdx.x;
  if (i >= n8) return;
  const float* src = (i < na8) ? (a + (size_t)i*8) : (b + ((size_t)(i-na8))*8);
  float4 x0 = *(const float4*)src;
  float4 x1 = *(const float4*)(src+4);
  float f[8] = {x0.x,x0.y,x0.z,x0.w,x1.x,x1.y,x1.z,x1.w};
  *(uint4*)&dst[(size_t)i*8] = pack8(f);
}

// ---------------- GEMM: C[M][N] = A[M][K] @ B[N][K]^T  (bf16 in, NT) ----------------
__global__ __launch_bounds__(256) void gemm_nt(const unsigned short* __restrict__ A,
    const unsigned short* __restrict__ Bw, void* __restrict__ Cout,
    const float* __restrict__ res, int Ntot, int K, int mode)
{
  __shared__ __align__(16) unsigned short a_s[128*72];
  __shared__ __align__(16) unsigned short b_s[128*72];
  const int tid = threadIdx.x;
  const int lane = tid & 63, wave = tid >> 6;
  const int wr = wave >> 1, wc = wave & 1;
  const long m0 = (long)blockIdx.y * 128, n0 = (long)blockIdx.x * 128;
  f32x16 acc[2][2];
  for (int qa=0;qa<2;qa++) for(int qb=0;qb<2;qb++) for (int e=0;e<16;e++) acc[qa][qb][e]=0.f;
  for (int k0 = 0; k0 < K; k0 += 64) {
    for (int c = 0; c < 4; c++) {
      int ch = c*256 + tid;
      int row = ch >> 3, off = (ch & 7)*8;
      *(uint4*)&a_s[row*72 + off] = *(const uint4*)&A[(size_t)(m0+row)*K + k0 + off];
      *(uint4*)&b_s[row*72 + off] = *(const uint4*)&Bw[(size_t)(n0+row)*K + k0 + off];
    }
    __syncthreads();
    for (int ks = 0; ks < 4; ks++) {
      const int koff = ks*16 + (lane>>5)*8;
      s16x8 af[2], bf[2];
      for (int q = 0; q < 2; q++) {
        af[q] = *(const s16x8*)&a_s[(wr*64 + q*32 + (lane&31))*72 + koff];
        bf[q] = *(const s16x8*)&b_s[(wc*64 + q*32 + (lane&31))*72 + koff];
      }
      for (int qr=0;qr<2;qr++)
        for (int qc2=0;qc2<2;qc2++)
          acc[qr][qc2] = __builtin_amdgcn_mfma_f32_32x32x16_bf16(af[qr], bf[qc2], acc[qr][qc2], 0,0,0);
    }
    __syncthreads();
  }
  for (int qr=0;qr<2;qr++)
    for (int qc2=0;qc2<2;qc2++)
      for (int e=0;e<16;e++){
        long row = m0 + wr*64 + qr*32 + (e&3) + 8*(e>>2) + 4*(lane>>5);
        long col = n0 + wc*64 + qc2*32 + (lane&31);
        size_t o = (size_t)row*Ntot + col;
        if (mode == 0) ((unsigned short*)Cout)[o] = f2b(acc[qr][qc2][e]);
        else           ((float*)Cout)[o] = acc[qr][qc2][e] + res[o];
      }
}

// ---------------- bdr GEMM (chunked): F[bhl][S][T+1] = QV[bh] @ relo_bh^T ----------------
__global__ __launch_bounds__(256) void gemm_bdr(const unsigned short* __restrict__ QV,
    const unsigned short* __restrict__ relo, unsigned short* __restrict__ FBD, int bh_base)
{
  __shared__ __align__(16) unsigned short a_s[128*72];
  __shared__ __align__(16) unsigned short b_s[128*72];
  const int tid = threadIdx.x, lane = tid&63, wave = tid>>6;
  const int wr = wave>>1, wc = wave&1;
  const int bhl = blockIdx.z;
  const int bh = bh_base + bhl, b = bh>>4, h = bh&15;
  const int m0 = blockIdx.y*128, n0 = blockIdx.x*128;
  const unsigned short* Ab = QV + (size_t)bh*S_*DH_;
  const unsigned short* Bb = relo + (size_t)b*1024 + h*64;
  unsigned short* Fb = FBD + (size_t)bhl*S_*(T_+1);
  for (int c=0;c<4;c++){
    int ch = c*256+tid; int row = ch>>3, off=(ch&7)*8;
    *(uint4*)&a_s[row*72+off] = *(const uint4*)&Ab[(size_t)(m0+row)*64+off];
    *(uint4*)&b_s[row*72+off] = *(const uint4*)&Bb[(size_t)(n0+row)*4096+off];
  }
  __syncthreads();
  f32x16 acc[2][2];
  for (int qa=0;qa<2;qa++) for(int qb=0;qb<2;qb++) for (int e=0;e<16;e++) acc[qa][qb][e]=0.f;
  for (int ks = 0; ks < 4; ks++) {
    const int koff = ks*16 + (lane>>5)*8;
    s16x8 af[2], bf[2];
    for (int q = 0; q < 2; q++) {
      af[q] = *(const s16x8*)&a_s[(wr*64 + q*32 + (lane&31))*72 + koff];
      bf[q] = *(const s16x8*)&b_s[(wc*64 + q*32 + (lane&31))*72 + koff];
    }
    for (int qa=0;qa<2;qa++)
      for (int qb=0;qb<2;qb++)
        acc[qa][qb] = __builtin_amdgcn_mfma_f32_32x32x16_bf16(af[qa], bf[qb], acc[qa][qb], 0,0,0);
  }
  for (int qa=0;qa<2;qa++)
    for (int qb=0;qb<2;qb++)
      for (int e=0;e<16;e++){
        int row = m0 + wr*64 + qa*32 + (e&3) + 8*(e>>2) + 4*(lane>>5);
        int col = n0 + wc*64 + qb*32 + (lane&31);
        Fb[(size_t)row*(T_+1) + col] = f2b(acc[qa][qb][e]);
      }
}

// ---------------- scatter: q + biases, per-head layout ----------------
__global__ __launch_bounds__(256) void scatter_quv(const unsigned short* __restrict__ qkvo,
   const float* __restrict__ u, const float* __restrict__ v,
   unsigned short* __restrict__ QU, unsigned short* __restrict__ QV)
{
  int gid = blockIdx.x*256 + threadIdx.x;   // B*H*S*8 = 524288
  int d0 = (gid & 7) * 8;
  int i  = (gid >> 3) & (S_-1);
  int bh = gid >> 13;
  int b = bh >> 4, h = bh & 15;
  size_t src = (size_t)((M_+i)*B_ + b)*3072 + h*64 + d0;
  uint4 q8 = *(const uint4*)&qkvo[src];
  float f[8];
  f[0]=b2f(q8.x&0xffff); f[1]=b2f(q8.x>>16); f[2]=b2f(q8.y&0xffff); f[3]=b2f(q8.y>>16);
  f[4]=b2f(q8.z&0xffff); f[5]=b2f(q8.z>>16); f[6]=b2f(q8.w&0xffff); f[7]=b2f(q8.w>>16);
  float fu[8], fv[8];
  for (int e=0;e<8;e++){ fu[e] = f[e] + u[h*64+d0+e]; fv[e] = f[e] + v[h*64+d0+e]; }
  size_t dst = ((size_t)bh*S_ + i)*64 + d0;
  *(uint4*)&QU[dst] = pack8(fu);
  *(uint4*)&QV[dst] = pack8(fv);
}

// ---------------- fused attention: AC via MFMA + BD staged from chunked FBD ----------------
// grid (bhl=16, itile=16, z=4), block 256 (4 waves, one 32x32 quad each).
// BD flat-diag rows are contiguous in j and uniformly misaligned by 7 elements:
// flat(i,j) = i*2048 + j + 1023; stage aligned 72-elem windows per row into LDS.
__global__ __launch_bounds__(256,3) void flash_attn2(
    const unsigned short* __restrict__ QU, const unsigned short* __restrict__ qkvo,
    const unsigned short* __restrict__ FBD, unsigned short* __restrict__ Opart,
    float* __restrict__ lpart, int bh_base)
{
  __shared__ __align__(16) unsigned short qu_s[64*72];
  __shared__ __align__(16) unsigned short k_s[64*72];
  __shared__ __align__(16) unsigned short vT_s[64*64];
  __shared__ __align__(16) unsigned short p_s[64*72];
  __shared__ __align__(16) unsigned short bd_s[64*76];

  const int tid = threadIdx.x, lane = tid&63, wave = tid>>6;
  const int bhl = blockIdx.x;
  const int bh = bh_base + bhl, b = bh>>4, h = bh&15;
  const int i0 = blockIdx.y*64;
  const int z = blockIdx.z;
  const int qr = wave>>1, qc = wave&1;
  const unsigned short* QUb = QU + (size_t)bh*S_*DH_;
  const unsigned short* Kg = qkvo + (size_t)b*3072 + 1024 + h*64;   // + t*12288
  const unsigned short* Vg = qkvo + (size_t)b*3072 + 2048 + h*64;
  const unsigned short* Fb = FBD + (size_t)bhl*S_*(T_+1);

  for (int c=0;c<2;c++){
    int ch = c*256+tid; int row = ch>>3, off=(ch&7)*8;
    *(uint4*)&qu_s[row*72+off] = *(const uint4*)&QUb[(size_t)(i0+row)*64 + off];
  }

  f32x16 acc_o;
  for (int e=0;e<16;e++) acc_o[e]=0.f;
  float lreg = 0.f;

  const int col = qc*32 + (lane&31);
  int rowl[16];
  for (int e=0;e<16;e++) rowl[e] = qr*32 + (e&3) + 8*(e>>2) + 4*(lane>>5);

  const int jbeg = z*(T_/4), jend = jbeg + (T_/4);
  for (int j0 = jbeg; j0 < jend; j0 += 64) {
    // stage K rows and V transposed (XOR-8 swizzle)
    for (int c=0;c<2;c++){
      int ch = c*256+tid; int row = ch>>3, off=(ch&7)*8;
      uint4 kk = *(const uint4*)&Kg[(size_t)(j0+row)*12288 + off];
      *(uint4*)&k_s[row*72+off] = kk;
      uint4 vv = *(const uint4*)&Vg[(size_t)(j0+row)*12288 + off];
      unsigned short ve[8] = {
        (unsigned short)(vv.x&0xffff),(unsigned short)(vv.x>>16),
        (unsigned short)(vv.y&0xffff),(unsigned short)(vv.y>>16),
        (unsigned short)(vv.z&0xffff),(unsigned short)(vv.z>>16),
        (unsigned short)(vv.w&0xffff),(unsigned short)(vv.w>>16)};
      for (int e=0;e<8;e++){
        int d = off + e;
        vT_s[d*64 + (row ^ (8*((d>>3)&7)))] = ve[e];
      }
    }
    // stage BD diag band: row r window [flat - 7, flat + 65), flat = (i0+r)*2048 + j0 + 1023
    for (int c=0;c<3;c++){
      int ch = c*256 + tid;
      if (ch < 576) {
        int row = ch/9, u = ch - row*9;
        *(uint4*)&bd_s[row*76 + u*8] =
            *(const uint4*)&Fb[(size_t)(i0+row)*2048 + j0 + 1016 + u*8];
      }
    }
    __syncthreads();

    // AC MFMA (one quad per wave)
    f32x16 acc;
    for (int e=0;e<16;e++) acc[e]=0.f;
    for (int ks=0; ks<4; ks++){
      const int koff = ks*16 + (lane>>5)*8;
      s16x8 a  = *(const s16x8*)&qu_s[(qr*32+(lane&31))*72 + koff];
      s16x8 bq = *(const s16x8*)&k_s[(qc*32+(lane&31))*72 + koff];
      acc = __builtin_amdgcn_mfma_f32_32x32x16_bf16(a, bq, acc, 0,0,0);
    }
    // scores -> exp -> bf16 P into p_s
    for (int e=0;e<16;e++){
      int r = rowl[e];
      int jd = j0 + col - (i0 + r);
      float bdv = (jd == M_+1) ? 0.f : b2f(bd_s[r*76 + col + 7]);
      float p = __expf((acc[e] + bdv) * 0.125f);
      p_s[r*72 + col] = f2b(p);
    }
    __syncthreads();

    // rowsum (4 threads per row)
    {
      int rr = tid>>2, cb = (tid&3)*16;
      uint4 x0 = *(const uint4*)&p_s[rr*72+cb];
      uint4 x1 = *(const uint4*)&p_s[rr*72+cb+8];
      unsigned vs[8] = {x0.x,x0.y,x0.z,x0.w,x1.x,x1.y,x1.z,x1.w};
      float s = 0.f;
      for (int e=0;e<8;e++) s += b2f((unsigned short)(vs[e]&0xffff)) + b2f((unsigned short)(vs[e]>>16));
      s += __shfl_xor(s, 1, 64);
      s += __shfl_xor(s, 2, 64);
      if ((tid&3)==0) lreg += s;
    }
    // PV MFMA
    for (int ks=0; ks<4; ks++){
      const int koff = ks*16 + (lane>>5)*8;
      s16x8 a = *(const s16x8*)&p_s[(qr*32+(lane&31))*72 + koff];
      int dcol = qc*32 + (lane&31);
      s16x8 bv = *(const s16x8*)&vT_s[dcol*64 + (koff ^ (8*((dcol>>3)&7)))];
      acc_o = __builtin_amdgcn_mfma_f32_32x32x16_bf16(a, bv, acc_o, 0,0,0);
    }
    __syncthreads();
  }

  // write partials
  if ((tid&3)==0)
    lpart[(size_t)z*(64*S_) + (size_t)bh*S_ + i0 + (tid>>2)] = lreg;
  for (int e=0;e<16;e++){
    size_t n = ((size_t)(i0+rowl[e])*B_ + b)*(H_*DH_) + h*DH_ + col;
    Opart[(size_t)z*(4096u*1024u) + n] = f2b(acc_o[e]);
  }
}

// ---------------- combine partials: AV = (Σz Oz)/(Σz lz) ----------------
__global__ __launch_bounds__(256) void combine_o(const unsigned short* __restrict__ Opart,
    const float* __restrict__ lpart, unsigned short* __restrict__ AV)
{
  int gid = blockIdx.x*256 + threadIdx.x;    // 524288
  size_t n = (size_t)gid*8;
  int h = (int)((n>>6) & 15);
  int b = (int)((n>>10) & 3);
  int i = (int)(n >> 12);
  int bh = b*16 + h;
  float l = 0.f;
  for (int z=0; z<4; z++) l += lpart[(size_t)z*(64*S_) + (size_t)bh*S_ + i];
  float inv = 1.f / l;
  float f[8] = {0,0,0,0,0,0,0,0};
  for (int z=0; z<4; z++){
    uint4 oz = *(const uint4*)&Opart[(size_t)z*(4096u*1024u) + n];
    unsigned a[4] = {oz.x,oz.y,oz.z,oz.w};
    for (int e=0;e<4;e++){
      f[2*e]   += b2f((unsigned short)(a[e]&0xffff));
      f[2*e+1] += b2f((unsigned short)(a[e]>>16));
    }
  }
  for (int e=0;e<8;e++) f[e] *= inv;
  *(uint4*)&AV[n] = pack8(f);
}

// ---------------- LayerNorm ----------------
__global__ __launch_bounds__(256) void ln_kernel(const float* __restrict__ y,
    const float* __restrict__ g, const float* __restrict__ be, float* __restrict__ o)
{
  __shared__ float red[8];
  int row = blockIdx.x, tid = threadIdx.x;
  const float* yr = y + (size_t)row*DM_;
  float v[4];
  for (int e=0;e<4;e++) v[e] = yr[tid + 256*e];
  float s = v[0]+v[1]+v[2]+v[3];
  for (int off=32; off>0; off>>=1) s += __shfl_down(s, off, 64);
  if ((tid&63)==0) red[tid>>6] = s;
  __syncthreads();
  if (tid==0) red[4] = red[0]+red[1]+red[2]+red[3];
  __syncthreads();
  float mu = red[4] * (1.f/DM_);
  __syncthreads();
  float q = 0.f;
  for (int e=0;e<4;e++){ float d = v[e]-mu; q += d*d; }
  for (int off=32; off>0; off>>=1) q += __shfl_down(q, off, 64);
  if ((tid&63)==0) red[tid>>6] = q;
  __syncthreads();
  if (tid==0) red[4] = red[0]+red[1]+red[2]+red[3];
  __syncthreads();
  float rstd = rsqrtf(red[4]*(1.f/DM_) + 1e-5f);
  for (int e=0;e<4;e++){
    int c = tid + 256*e;
    o[(size_t)row*DM_ + c] = g[c]*(v[e]-mu)*rstd + be[c];
  }
}

// ---------------- launch ----------------
extern "C" void kernel_launch(void* const* d_in, const int* in_sizes, int n_in,
                              void* d_out, int out_size, void* d_ws, size_t ws_size,
                              hipStream_t stream)
{
  const float* x    = (const float*)d_in[0];
  const float* mem  = (const float*)d_in[1];
  const float* pos  = (const float*)d_in[2];
  const float* pbu  = (const float*)d_in[3];
  const float* pbv  = (const float*)d_in[4];
  const float* wqkv = (const float*)d_in[5];
  const float* wrel = (const float*)d_in[6];
  const float* wo   = (const float*)d_in[7];
  const float* gam  = (const float*)d_in[8];
  const float* bet  = (const float*)d_in[9];
  float* out = (float*)d_out;

  char* w = (char*)d_ws;
  // FBD chunk region [0, 67,141,632). Overlays (lifetimes disjoint from FBD):
  //   pre-bdr: cast transients c16/pos16/wq16/wr16
  //   post-flash: yf (w+0, 16.8MB) and av16 (w+16.8MB, 8.4MB)
  unsigned short* FBD   = (unsigned short*)(w + 0);
  unsigned short* c16   = (unsigned short*)(w + 0);
  unsigned short* pos16 = (unsigned short*)(w + 16777216);
  unsigned short* wq16  = (unsigned short*)(w + 33554432);
  unsigned short* wr16  = (unsigned short*)(w + 39845888);
  float*          yf    = (float*)(w + 0);
  unsigned short* av16  = (unsigned short*)(w + 16777216);
  unsigned short* qkvo  = (unsigned short*)(w + 67141632);   // 50,331,648
  unsigned short* relo  = (unsigned short*)(w + 117473280);  // 16,777,216
  unsigned short* wo16  = (unsigned short*)(w + 134250496);  //  2,097,152
  unsigned short* QUb   = (unsigned short*)(w + 136347648);  //  8,388,608
  unsigned short* QVb   = (unsigned short*)(w + 144736256);  //  8,388,608
  unsigned short* Opart = (unsigned short*)(w + 153124864);  // 33,554,432
  float*          lpart = (float*)(w + 186679296);           //  1,048,576 -> total 187,727,872

  cast_cat<<<4096, 256, 0, stream>>>(mem, x, c16, 1048576, 524288);
  cast_cat<<<4096, 256, 0, stream>>>(pos, pos, pos16, 1048576, 1048576);
  cast_cat<<<1536, 256, 0, stream>>>(wqkv, wqkv, wq16, 393216, 393216);
  cast_cat<<< 512, 256, 0, stream>>>(wrel, wrel, wr16, 131072, 131072);
  cast_cat<<< 512, 256, 0, stream>>>(wo,   wo,   wo16, 131072, 131072);

  gemm_nt<<<dim3(24,64), 256, 0, stream>>>(c16,   wq16, (void*)qkvo, nullptr, 3072, 1024, 0);
  gemm_nt<<<dim3(8,64),  256, 0, stream>>>(pos16, wr16, (void*)relo, nullptr, 1024, 1024, 0);

  scatter_quv<<<2048, 256, 0, stream>>>(qkvo, pbu, pbv, QUb, QVb);

  for (int cchunk = 0; cchunk < 4; cchunk++) {
    int bh_base = cchunk*16;
    gemm_bdr<<<dim3(16,8,16), 256, 0, stream>>>(QVb, relo, FBD, bh_base);
    flash_attn2<<<dim3(16,16,4), 256, 0, stream>>>(QUb, qkvo, FBD, Opart, lpart, bh_base);
  }
  combine_o<<<2048, 256, 0, stream>>>(Opart, lpart, av16);

  gemm_nt<<<dim3(8,32), 256, 0, stream>>>(av16, wo16, (void*)yf, x, 1024, 1024, 1);
  ln_kernel<<<4096, 256, 0, stream>>>(yf, gam, bet, out);
}

// Round 6
// 552.999 us; speedup vs baseline: 1.0785x; 1.0785x over previous
//
#include <hip/hip_runtime.h>

#define S_ 1024
#define M_ 1024
#define T_ 2048
#define B_ 4
#define H_ 16
#define DM_ 1024
#define DH_ 64

typedef __attribute__((ext_vector_type(8))) short s16x8;
typedef __attribute__((ext_vector_type(16))) float f32x16;

__device__ __forceinline__ unsigned short f2b(float x){
  unsigned int u = __float_as_uint(x);
  u = (u + 0x7fffu + ((u>>16)&1u)) >> 16;
  return (unsigned short)u;
}
__device__ __forceinline__ float b2f(unsigned short h){
  return __uint_as_float(((unsigned int)h)<<16);
}
__device__ __forceinline__ uint4 pack8(const float* v){
  uint4 o;
  o.x = (unsigned)f2b(v[0]) | ((unsigned)f2b(v[1])<<16);
  o.y = (unsigned)f2b(v[2]) | ((unsigned)f2b(v[3])<<16);
  o.z = (unsigned)f2b(v[4]) | ((unsigned)f2b(v[5])<<16);
  o.w = (unsigned)f2b(v[6]) | ((unsigned)f2b(v[7])<<16);
  return o;
}
// async global->LDS, 16B per lane. LDS dest: per-lane ptr contiguous in lane order.
__device__ __forceinline__ void glds16(const unsigned short* g, unsigned short* l){
  __builtin_amdgcn_global_load_lds((const __attribute__((address_space(1))) void*)g,
                                   (__attribute__((address_space(3))) void*)l, 16, 0, 0);
}

// ---------------- cast kernels ----------------
__global__ __launch_bounds__(256) void cast_cat(const float* __restrict__ a,
    const float* __restrict__ b, unsigned short* __restrict__ dst, int n8, int na8)
{
  int i = blockIdx.x*256 + threadIdx.x;
  if (i >= n8) return;
  const float* src = (i < na8) ? (a + (size_t)i*8) : (b + ((size_t)(i-na8))*8);
  float4 x0 = *(const float4*)src;
  float4 x1 = *(const float4*)(src+4);
  float f[8] = {x0.x,x0.y,x0.z,x0.w,x1.x,x1.y,x1.z,x1.w};
  *(uint4*)&dst[(size_t)i*8] = pack8(f);
}

// ---------------- GEMM: C[M][N] = A[M][K] @ B[N][K]^T  (bf16 in, NT) ----------------
// glds staging into unpadded LDS; global column XOR-permuted per lane so the
// fragment ds_read_b128 self-consistently finds its k-block.
__global__ __launch_bounds__(256) void gemm_nt(const unsigned short* __restrict__ A,
    const unsigned short* __restrict__ Bw, void* __restrict__ Cout,
    const float* __restrict__ res, int Ntot, int K, int mode)
{
  __shared__ __align__(16) unsigned short a_s[128*64];
  __shared__ __align__(16) unsigned short b_s[128*64];
  const int tid = threadIdx.x;
  const int lane = tid & 63, wave = tid >> 6;
  const int wr = wave >> 1, wc = wave & 1;
  const long m0 = (long)blockIdx.y * 128, n0 = (long)blockIdx.x * 128;
  f32x16 acc[2][2];
  for (int qa=0;qa<2;qa++) for(int qb=0;qb<2;qb++) for (int e=0;e<16;e++) acc[qa][qb][e]=0.f;
  int srow[4], scol[4];
  for (int c = 0; c < 4; c++) {
    int ch = c*256 + tid;
    srow[c] = ch >> 3;
    scol[c] = (((ch & 7) ^ (srow[c] & 7))) * 8;
  }
  for (int k0 = 0; k0 < K; k0 += 64) {
    for (int c = 0; c < 4; c++) {
      int ch = c*256 + tid;
      glds16(&A[(size_t)(m0+srow[c])*K + k0 + scol[c]], &a_s[ch*8]);
      glds16(&Bw[(size_t)(n0+srow[c])*K + k0 + scol[c]], &b_s[ch*8]);
    }
    __syncthreads();
    for (int ks = 0; ks < 4; ks++) {
      const int kb = ks*2 + (lane>>5);   // 16B-block index
      s16x8 af[2], bf[2];
      for (int q = 0; q < 2; q++) {
        int ra = wr*64 + q*32 + (lane&31);
        int rb = wc*64 + q*32 + (lane&31);
        af[q] = *(const s16x8*)&a_s[ra*64 + ((kb ^ (ra&7))<<3)];
        bf[q] = *(const s16x8*)&b_s[rb*64 + ((kb ^ (rb&7))<<3)];
      }
      for (int qr=0;qr<2;qr++)
        for (int qc2=0;qc2<2;qc2++)
          acc[qr][qc2] = __builtin_amdgcn_mfma_f32_32x32x16_bf16(af[qr], bf[qc2], acc[qr][qc2], 0,0,0);
    }
    __syncthreads();
  }
  for (int qr=0;qr<2;qr++)
    for (int qc2=0;qc2<2;qc2++)
      for (int e=0;e<16;e++){
        long row = m0 + wr*64 + qr*32 + (e&3) + 8*(e>>2) + 4*(lane>>5);
        long col = n0 + wc*64 + qc2*32 + (lane&31);
        size_t o = (size_t)row*Ntot + col;
        if (mode == 0) ((unsigned short*)Cout)[o] = f2b(acc[qr][qc2][e]);
        else           ((float*)Cout)[o] = acc[qr][qc2][e] + res[o];
      }
}

// ---------------- bdr GEMM (chunked): F[bhl][S][T+1] = QV[bh] @ relo_bh^T ----------------
__global__ __launch_bounds__(256) void gemm_bdr(const unsigned short* __restrict__ QV,
    const unsigned short* __restrict__ relo, unsigned short* __restrict__ FBD, int bh_base)
{
  __shared__ __align__(16) unsigned short a_s[128*72];
  __shared__ __align__(16) unsigned short b_s[128*72];
  const int tid = threadIdx.x, lane = tid&63, wave = tid>>6;
  const int wr = wave>>1, wc = wave&1;
  const int bhl = blockIdx.z;
  const int bh = bh_base + bhl, b = bh>>4, h = bh&15;
  const int m0 = blockIdx.y*128, n0 = blockIdx.x*128;
  const unsigned short* Ab = QV + (size_t)bh*S_*DH_;
  const unsigned short* Bb = relo + (size_t)b*1024 + h*64;
  unsigned short* Fb = FBD + (size_t)bhl*S_*(T_+1);
  for (int c=0;c<4;c++){
    int ch = c*256+tid; int row = ch>>3, off=(ch&7)*8;
    *(uint4*)&a_s[row*72+off] = *(const uint4*)&Ab[(size_t)(m0+row)*64+off];
    *(uint4*)&b_s[row*72+off] = *(const uint4*)&Bb[(size_t)(n0+row)*4096+off];
  }
  __syncthreads();
  f32x16 acc[2][2];
  for (int qa=0;qa<2;qa++) for(int qb=0;qb<2;qb++) for (int e=0;e<16;e++) acc[qa][qb][e]=0.f;
  for (int ks = 0; ks < 4; ks++) {
    const int koff = ks*16 + (lane>>5)*8;
    s16x8 af[2], bf[2];
    for (int q = 0; q < 2; q++) {
      af[q] = *(const s16x8*)&a_s[(wr*64 + q*32 + (lane&31))*72 + koff];
      bf[q] = *(const s16x8*)&b_s[(wc*64 + q*32 + (lane&31))*72 + koff];
    }
    for (int qa=0;qa<2;qa++)
      for (int qb=0;qb<2;qb++)
        acc[qa][qb] = __builtin_amdgcn_mfma_f32_32x32x16_bf16(af[qa], bf[qb], acc[qa][qb], 0,0,0);
  }
  for (int qa=0;qa<2;qa++)
    for (int qb=0;qb<2;qb++)
      for (int e=0;e<16;e++){
        int row = m0 + wr*64 + qa*32 + (e&3) + 8*(e>>2) + 4*(lane>>5);
        int col = n0 + wc*64 + qb*32 + (lane&31);
        Fb[(size_t)row*(T_+1) + col] = f2b(acc[qa][qb][e]);
      }
}

// ---------------- scatter: q + biases, per-head layout ----------------
__global__ __launch_bounds__(256) void scatter_quv(const unsigned short* __restrict__ qkvo,
   const float* __restrict__ u, const float* __restrict__ v,
   unsigned short* __restrict__ QU, unsigned short* __restrict__ QV)
{
  int gid = blockIdx.x*256 + threadIdx.x;   // B*H*S*8 = 524288
  int d0 = (gid & 7) * 8;
  int i  = (gid >> 3) & (S_-1);
  int bh = gid >> 13;
  int b = bh >> 4, h = bh & 15;
  size_t src = (size_t)((M_+i)*B_ + b)*3072 + h*64 + d0;
  uint4 q8 = *(const uint4*)&qkvo[src];
  float f[8];
  f[0]=b2f(q8.x&0xffff); f[1]=b2f(q8.x>>16); f[2]=b2f(q8.y&0xffff); f[3]=b2f(q8.y>>16);
  f[4]=b2f(q8.z&0xffff); f[5]=b2f(q8.z>>16); f[6]=b2f(q8.w&0xffff); f[7]=b2f(q8.w>>16);
  float fu[8], fv[8];
  for (int e=0;e<8;e++){ fu[e] = f[e] + u[h*64+d0+e]; fv[e] = f[e] + v[h*64+d0+e]; }
  size_t dst = ((size_t)bh*S_ + i)*64 + d0;
  *(uint4*)&QU[dst] = pack8(fu);
  *(uint4*)&QV[dst] = pack8(fv);
}

// ---------------- scatter_vt: VT[bh][d][t] = V[t][b][h][d] (LDS transpose) ----------------
__global__ __launch_bounds__(256) void scatter_vt(const unsigned short* __restrict__ qkvo,
    unsigned short* __restrict__ VT)
{
  __shared__ __align__(16) unsigned short v_s[64*72];
  const int tid = threadIdx.x;
  const int bh = blockIdx.x, b = bh>>4, h = bh&15;
  const int t0 = blockIdx.y*64;
  const unsigned short* Vg = qkvo + (size_t)b*3072 + 2048 + h*64;
  for (int c=0;c<2;c++){                       // FIX: 2 chunks -> all 64 rows staged
    int ch = c*256 + tid;
    int r = ch>>3, off = (ch&7)*8;
    *(uint4*)&v_s[r*72+off] = *(const uint4*)&Vg[(size_t)(t0+r)*12288 + off];
  }
  __syncthreads();
  for (int c=0;c<2;c++){
    int ch = c*256 + tid;
    int d = ch>>3, toff = (ch&7)*8;
    unsigned short vals[8];
    for (int e=0;e<8;e++) vals[e] = v_s[(toff+e)*72 + d];
    uint4 pk;
    pk.x = (unsigned)vals[0] | ((unsigned)vals[1]<<16);
    pk.y = (unsigned)vals[2] | ((unsigned)vals[3]<<16);
    pk.z = (unsigned)vals[4] | ((unsigned)vals[5]<<16);
    pk.w = (unsigned)vals[6] | ((unsigned)vals[7]<<16);
    *(uint4*)&VT[((size_t)bh*64 + d)*T_ + t0 + toff] = pk;
  }
}

// ---------------- zero accumulators ----------------
__global__ __launch_bounds__(256) void zero_acc(float4* __restrict__ p, int n4)
{
  int i = blockIdx.x*256 + threadIdx.x;
  if (i < n4) p[i] = make_float4(0.f,0.f,0.f,0.f);
}

// ---------------- fused attention v3 ----------------
// grid (bhl=16, itile=16, z=4), block 256 (4 waves, one 32x32 quad each).
__global__ __launch_bounds__(256,4) void flash_attn3(
    const unsigned short* __restrict__ QU, const unsigned short* __restrict__ qkvo,
    const unsigned short* __restrict__ VT, const unsigned short* __restrict__ FBD,
    float* __restrict__ Oacc, float* __restrict__ lacc, int bh_base)
{
  __shared__ __align__(16) unsigned short qu_s[64*64];
  __shared__ __align__(16) unsigned short k_s[64*64];
  __shared__ __align__(16) unsigned short vT_s[64*64];
  __shared__ __align__(16) unsigned short p_s[64*72];

  const int tid = threadIdx.x, lane = tid&63, wave = tid>>6;
  const int bhl = blockIdx.x;
  const int bh = bh_base + bhl, b = bh>>4, h = bh&15;
  const int i0 = blockIdx.y*64;
  const int z = blockIdx.z;
  const int qr = wave>>1, qc = wave&1;
  const unsigned short* QUb = QU + (size_t)bh*S_*DH_;
  const unsigned short* Kg  = qkvo + (size_t)b*3072 + 1024 + h*64;   // + t*12288
  const unsigned short* VTb = VT + (size_t)bh*64*T_;
  const unsigned short* Fb  = FBD + (size_t)bhl*S_*(T_+1);

  int srow[2], scol[2];
  for (int c=0;c<2;c++){
    int ch = c*256 + tid;
    srow[c] = ch>>3;
    scol[c] = ((ch&7) ^ (srow[c]&7))*8;
  }
  for (int c=0;c<2;c++){
    int ch = c*256+tid;
    glds16(&QUb[(size_t)(i0+srow[c])*64 + scol[c]], &qu_s[ch*8]);
  }

  f32x16 acc_o;
  for (int e=0;e<16;e++) acc_o[e]=0.f;
  float lreg = 0.f;

  const int col = qc*32 + (lane&31);
  int rowl[16];
  for (int e=0;e<16;e++) rowl[e] = qr*32 + (e&3) + 8*(e>>2) + 4*(lane>>5);

  const int jbeg = z*(T_/4), jend = jbeg + (T_/4);
  for (int j0 = jbeg; j0 < jend; j0 += 64) {
    for (int c=0;c<2;c++){
      int ch = c*256+tid;
      glds16(&Kg[(size_t)(j0+srow[c])*12288 + scol[c]], &k_s[ch*8]);
      glds16(&VTb[(size_t)srow[c]*T_ + j0 + scol[c]], &vT_s[ch*8]);
    }
    unsigned short bdu[16];
    const int jj = j0 + col;
    for (int e=0;e<16;e++)
      bdu[e] = Fb[(size_t)(i0+rowl[e])*T_ + jj + (S_-1)];
    __syncthreads();

    f32x16 acc;
    for (int e=0;e<16;e++) acc[e]=0.f;
    for (int ks=0; ks<4; ks++){
      const int kb = ks*2 + (lane>>5);
      int ra = qr*32 + (lane&31);
      int rk = qc*32 + (lane&31);
      s16x8 a  = *(const s16x8*)&qu_s[ra*64 + ((kb ^ (ra&7))<<3)];
      s16x8 bq = *(const s16x8*)&k_s[rk*64 + ((kb ^ (rk&7))<<3)];
      acc = __builtin_amdgcn_mfma_f32_32x32x16_bf16(a, bq, acc, 0,0,0);
    }
    for (int e=0;e<16;e++){
      int r = rowl[e];
      int jd = jj - (i0 + r);
      float bdv = (jd == M_+1) ? 0.f : b2f(bdu[e]);
      float p = __expf((acc[e] + bdv) * 0.125f);
      p_s[r*72 + col] = f2b(p);
    }
    __syncthreads();

    {
      int rr = tid>>2, cb = (tid&3)*16;
      uint4 x0 = *(const uint4*)&p_s[rr*72+cb];
      uint4 x1 = *(const uint4*)&p_s[rr*72+cb+8];
      unsigned vs[8] = {x0.x,x0.y,x0.z,x0.w,x1.x,x1.y,x1.z,x1.w};
      float s = 0.f;
      for (int e=0;e<8;e++) s += b2f((unsigned short)(vs[e]&0xffff)) + b2f((unsigned short)(vs[e]>>16));
      s += __shfl_xor(s, 1, 64);
      s += __shfl_xor(s, 2, 64);
      if ((tid&3)==0) lreg += s;
    }
    for (int ks=0; ks<4; ks++){
      const int koff = ks*16 + (lane>>5)*8;
      const int kb = ks*2 + (lane>>5);
      s16x8 a = *(const s16x8*)&p_s[(qr*32+(lane&31))*72 + koff];
      int dcol = qc*32 + (lane&31);
      s16x8 bv = *(const s16x8*)&vT_s[dcol*64 + ((kb ^ (dcol&7))<<3)];
      acc_o = __builtin_amdgcn_mfma_f32_32x32x16_bf16(a, bv, acc_o, 0,0,0);
    }
    __syncthreads();
  }

  if ((tid&3)==0)
    atomicAdd(&lacc[(size_t)bh*S_ + i0 + (tid>>2)], lreg);
  for (int e=0;e<16;e++){
    size_t n = ((size_t)(i0+rowl[e])*B_ + b)*(H_*DH_) + h*DH_ + col;
    atomicAdd(&Oacc[n], acc_o[e]);
  }
}

// ---------------- combine: AV = Oacc / lacc ----------------
__global__ __launch_bounds__(256) void combine_o(const float* __restrict__ Oacc,
    const float* __restrict__ lacc, unsigned short* __restrict__ AV)
{
  int gid = blockIdx.x*256 + threadIdx.x;    // 524288
  size_t n = (size_t)gid*8;
  int h = (int)((n>>6) & 15);
  int b = (int)((n>>10) & 3);
  int i = (int)(n >> 12);
  int bh = b*16 + h;
  float inv = 1.f / lacc[(size_t)bh*S_ + i];
  float4 o0 = *(const float4*)&Oacc[n];
  float4 o1 = *(const float4*)&Oacc[n+4];
  float f[8] = {o0.x*inv,o0.y*inv,o0.z*inv,o0.w*inv,o1.x*inv,o1.y*inv,o1.z*inv,o1.w*inv};
  *(uint4*)&AV[n] = pack8(f);
}

// ---------------- LayerNorm ----------------
__global__ __launch_bounds__(256) void ln_kernel(const float* __restrict__ y,
    const float* __restrict__ g, const float* __restrict__ be, float* __restrict__ o)
{
  __shared__ float red[8];
  int row = blockIdx.x, tid = threadIdx.x;
  const float* yr = y + (size_t)row*DM_;
  float v[4];
  for (int e=0;e<4;e++) v[e] = yr[tid + 256*e];
  float s = v[0]+v[1]+v[2]+v[3];
  for (int off=32; off>0; off>>=1) s += __shfl_down(s, off, 64);
  if ((tid&63)==0) red[tid>>6] = s;
  __syncthreads();
  if (tid==0) red[4] = red[0]+red[1]+red[2]+red[3];
  __syncthreads();
  float mu = red[4] * (1.f/DM_);
  __syncthreads();
  float q = 0.f;
  for (int e=0;e<4;e++){ float d = v[e]-mu; q += d*d; }
  for (int off=32; off>0; off>>=1) q += __shfl_down(q, off, 64);
  if ((tid&63)==0) red[tid>>6] = q;
  __syncthreads();
  if (tid==0) red[4] = red[0]+red[1]+red[2]+red[3];
  __syncthreads();
  float rstd = rsqrtf(red[4]*(1.f/DM_) + 1e-5f);
  for (int e=0;e<4;e++){
    int c = tid + 256*e;
    o[(size_t)row*DM_ + c] = g[c]*(v[e]-mu)*rstd + be[c];
  }
}

// ---------------- launch ----------------
extern "C" void kernel_launch(void* const* d_in, const int* in_sizes, int n_in,
                              void* d_out, int out_size, void* d_ws, size_t ws_size,
                              hipStream_t stream)
{
  const float* x    = (const float*)d_in[0];
  const float* mem  = (const float*)d_in[1];
  const float* pos  = (const float*)d_in[2];
  const float* pbu  = (const float*)d_in[3];
  const float* pbv  = (const float*)d_in[4];
  const float* wqkv = (const float*)d_in[5];
  const float* wrel = (const float*)d_in[6];
  const float* wo   = (const float*)d_in[7];
  const float* gam  = (const float*)d_in[8];
  const float* bet  = (const float*)d_in[9];
  float* out = (float*)d_out;

  char* w = (char*)d_ws;
  // FBD chunk region [0, 67,141,632). Overlays: casts pre-bdr; yf/av16 post-flash.
  unsigned short* FBD   = (unsigned short*)(w + 0);
  unsigned short* c16   = (unsigned short*)(w + 0);
  unsigned short* pos16 = (unsigned short*)(w + 16777216);
  unsigned short* wq16  = (unsigned short*)(w + 33554432);
  unsigned short* wr16  = (unsigned short*)(w + 39845888);
  float*          yf    = (float*)(w + 0);
  unsigned short* av16  = (unsigned short*)(w + 16777216);
  unsigned short* qkvo  = (unsigned short*)(w + 67141632);   // 50,331,648
  unsigned short* relo  = (unsigned short*)(w + 117473280);  // 16,777,216
  unsigned short* wo16  = (unsigned short*)(w + 134250496);  //  2,097,152
  unsigned short* QUb   = (unsigned short*)(w + 136347648);  //  8,388,608
  unsigned short* QVb   = (unsigned short*)(w + 144736256);  //  8,388,608
  unsigned short* VT    = (unsigned short*)(w + 153124864);  // 16,777,216
  float*          Oacc  = (float*)(w + 169902080);           // 16,777,216
  float*          lacc  = (float*)(w + 186679296);           //    262,144 -> total 186,941,440

  cast_cat<<<4096, 256, 0, stream>>>(mem, x, c16, 1048576, 524288);
  cast_cat<<<4096, 256, 0, stream>>>(pos, pos, pos16, 1048576, 1048576);
  cast_cat<<<1536, 256, 0, stream>>>(wqkv, wqkv, wq16, 393216, 393216);
  cast_cat<<< 512, 256, 0, stream>>>(wrel, wrel, wr16, 131072, 131072);
  cast_cat<<< 512, 256, 0, stream>>>(wo,   wo,   wo16, 131072, 131072);

  gemm_nt<<<dim3(24,64), 256, 0, stream>>>(c16,   wq16, (void*)qkvo, nullptr, 3072, 1024, 0);
  gemm_nt<<<dim3(8,64),  256, 0, stream>>>(pos16, wr16, (void*)relo, nullptr, 1024, 1024, 0);

  scatter_quv<<<2048, 256, 0, stream>>>(qkvo, pbu, pbv, QUb, QVb);
  scatter_vt<<<dim3(64,32), 256, 0, stream>>>(qkvo, VT);
  zero_acc<<<4160, 256, 0, stream>>>((float4*)Oacc, 4259840/4);   // Oacc + lacc (contiguous)

  for (int cchunk = 0; cchunk < 4; cchunk++) {
    int bh_base = cchunk*16;
    gemm_bdr<<<dim3(16,8,16), 256, 0, stream>>>(QVb, relo, FBD, bh_base);
    flash_attn3<<<dim3(16,16,4), 256, 0, stream>>>(QUb, qkvo, VT, FBD, Oacc, lacc, bh_base);
  }
  combine_o<<<2048, 256, 0, stream>>>(Oacc, lacc, av16);

  gemm_nt<<<dim3(8,32), 256, 0, stream>>>(av16, wo16, (void*)yf, x, 1024, 1024, 1);
  ln_kernel<<<4096, 256, 0, stream>>>(yf, gam, bet, out);
}

// Round 7
// 531.848 us; speedup vs baseline: 1.1214x; 1.0398x over previous
//
#include <hip/hip_runtime.h>

#define S_ 1024
#define M_ 1024
#define T_ 2048
#define B_ 4
#define H_ 16
#define DM_ 1024
#define DH_ 64

typedef __attribute__((ext_vector_type(8))) short s16x8;
typedef __attribute__((ext_vector_type(16))) float f32x16;

__device__ __forceinline__ unsigned short f2b(float x){
  unsigned int u = __float_as_uint(x);
  u = (u + 0x7fffu + ((u>>16)&1u)) >> 16;
  return (unsigned short)u;
}
__device__ __forceinline__ float b2f(unsigned short h){
  return __uint_as_float(((unsigned int)h)<<16);
}
__device__ __forceinline__ uint4 pack8(const float* v){
  uint4 o;
  o.x = (unsigned)f2b(v[0]) | ((unsigned)f2b(v[1])<<16);
  o.y = (unsigned)f2b(v[2]) | ((unsigned)f2b(v[3])<<16);
  o.z = (unsigned)f2b(v[4]) | ((unsigned)f2b(v[5])<<16);
  o.w = (unsigned)f2b(v[6]) | ((unsigned)f2b(v[7])<<16);
  return o;
}
__device__ __forceinline__ void glds16(const unsigned short* g, unsigned short* l){
  __builtin_amdgcn_global_load_lds((const __attribute__((address_space(1))) void*)g,
                                   (__attribute__((address_space(3))) void*)l, 16, 0, 0);
}

// ---------------- cast kernels ----------------
__global__ __launch_bounds__(256) void cast_cat(const float* __restrict__ a,
    const float* __restrict__ b, unsigned short* __restrict__ dst, int n8, int na8)
{
  int i = blockIdx.x*256 + threadIdx.x;
  if (i >= n8) return;
  const float* src = (i < na8) ? (a + (size_t)i*8) : (b + ((size_t)(i-na8))*8);
  float4 x0 = *(const float4*)src;
  float4 x1 = *(const float4*)(src+4);
  float f[8] = {x0.x,x0.y,x0.z,x0.w,x1.x,x1.y,x1.z,x1.w};
  *(uint4*)&dst[(size_t)i*8] = pack8(f);
}

// ---------------- GEMM: C[M][N] = A[M][K] @ B[N][K]^T  (bf16 in, NT) ----------------
__global__ __launch_bounds__(256) void gemm_nt(const unsigned short* __restrict__ A,
    const unsigned short* __restrict__ Bw, void* __restrict__ Cout,
    const float* __restrict__ res, int Ntot, int K, int mode)
{
  __shared__ __align__(16) unsigned short a_s[128*64];
  __shared__ __align__(16) unsigned short b_s[128*64];
  const int tid = threadIdx.x;
  const int lane = tid & 63, wave = tid >> 6;
  const int wr = wave >> 1, wc = wave & 1;
  const long m0 = (long)blockIdx.y * 128, n0 = (long)blockIdx.x * 128;
  f32x16 acc[2][2];
  for (int qa=0;qa<2;qa++) for(int qb=0;qb<2;qb++) for (int e=0;e<16;e++) acc[qa][qb][e]=0.f;
  int srow[4], scol[4];
  for (int c = 0; c < 4; c++) {
    int ch = c*256 + tid;
    srow[c] = ch >> 3;
    scol[c] = (((ch & 7) ^ (srow[c] & 7))) * 8;
  }
  for (int k0 = 0; k0 < K; k0 += 64) {
    for (int c = 0; c < 4; c++) {
      int ch = c*256 + tid;
      glds16(&A[(size_t)(m0+srow[c])*K + k0 + scol[c]], &a_s[ch*8]);
      glds16(&Bw[(size_t)(n0+srow[c])*K + k0 + scol[c]], &b_s[ch*8]);
    }
    __syncthreads();
    for (int ks = 0; ks < 4; ks++) {
      const int kb = ks*2 + (lane>>5);
      s16x8 af[2], bf[2];
      for (int q = 0; q < 2; q++) {
        int ra = wr*64 + q*32 + (lane&31);
        int rb = wc*64 + q*32 + (lane&31);
        af[q] = *(const s16x8*)&a_s[ra*64 + ((kb ^ (ra&7))<<3)];
        bf[q] = *(const s16x8*)&b_s[rb*64 + ((kb ^ (rb&7))<<3)];
      }
      for (int qr=0;qr<2;qr++)
        for (int qc2=0;qc2<2;qc2++)
          acc[qr][qc2] = __builtin_amdgcn_mfma_f32_32x32x16_bf16(af[qr], bf[qc2], acc[qr][qc2], 0,0,0);
    }
    __syncthreads();
  }
  for (int qr=0;qr<2;qr++)
    for (int qc2=0;qc2<2;qc2++)
      for (int e=0;e<16;e++){
        long row = m0 + wr*64 + qr*32 + (e&3) + 8*(e>>2) + 4*(lane>>5);
        long col = n0 + wc*64 + qc2*32 + (lane&31);
        size_t o = (size_t)row*Ntot + col;
        if (mode == 0) ((unsigned short*)Cout)[o] = f2b(acc[qr][qc2][e]);
        else           ((float*)Cout)[o] = acc[qr][qc2][e] + res[o];
      }
}

// ---------------- scatter: q + biases, per-head layout ----------------
__global__ __launch_bounds__(256) void scatter_quv(const unsigned short* __restrict__ qkvo,
   const float* __restrict__ u, const float* __restrict__ v,
   unsigned short* __restrict__ QU, unsigned short* __restrict__ QV)
{
  int gid = blockIdx.x*256 + threadIdx.x;   // B*H*S*8 = 524288
  int d0 = (gid & 7) * 8;
  int i  = (gid >> 3) & (S_-1);
  int bh = gid >> 13;
  int b = bh >> 4, h = bh & 15;
  size_t src = (size_t)((M_+i)*B_ + b)*3072 + h*64 + d0;
  uint4 q8 = *(const uint4*)&qkvo[src];
  float f[8];
  f[0]=b2f(q8.x&0xffff); f[1]=b2f(q8.x>>16); f[2]=b2f(q8.y&0xffff); f[3]=b2f(q8.y>>16);
  f[4]=b2f(q8.z&0xffff); f[5]=b2f(q8.z>>16); f[6]=b2f(q8.w&0xffff); f[7]=b2f(q8.w>>16);
  float fu[8], fv[8];
  for (int e=0;e<8;e++){ fu[e] = f[e] + u[h*64+d0+e]; fv[e] = f[e] + v[h*64+d0+e]; }
  size_t dst = ((size_t)bh*S_ + i)*64 + d0;
  *(uint4*)&QU[dst] = pack8(fu);
  *(uint4*)&QV[dst] = pack8(fv);
}

// ---------------- scatter_vt: VT[bh][d][t] = V[t][b][h][d] (LDS transpose) ----------------
__global__ __launch_bounds__(256) void scatter_vt(const unsigned short* __restrict__ qkvo,
    unsigned short* __restrict__ VT)
{
  __shared__ __align__(16) unsigned short v_s[64*72];
  const int tid = threadIdx.x;
  const int bh = blockIdx.x, b = bh>>4, h = bh&15;
  const int t0 = blockIdx.y*64;
  const unsigned short* Vg = qkvo + (size_t)b*3072 + 2048 + h*64;
  for (int c=0;c<2;c++){
    int ch = c*256 + tid;
    int r = ch>>3, off = (ch&7)*8;
    *(uint4*)&v_s[r*72+off] = *(const uint4*)&Vg[(size_t)(t0+r)*12288 + off];
  }
  __syncthreads();
  for (int c=0;c<2;c++){
    int ch = c*256 + tid;
    int d = ch>>3, toff = (ch&7)*8;
    unsigned short vals[8];
    for (int e=0;e<8;e++) vals[e] = v_s[(toff+e)*72 + d];
    uint4 pk;
    pk.x = (unsigned)vals[0] | ((unsigned)vals[1]<<16);
    pk.y = (unsigned)vals[2] | ((unsigned)vals[3]<<16);
    pk.z = (unsigned)vals[4] | ((unsigned)vals[5]<<16);
    pk.w = (unsigned)vals[6] | ((unsigned)vals[7]<<16);
    *(uint4*)&VT[((size_t)bh*64 + d)*T_ + t0 + toff] = pk;
  }
}

// ---------------- fused attention v4: BD computed in-kernel via band GEMM ----------------
// grid (bh=64, itile=16), block 256, 4 waves. Per j-tile of 64:
//   BD[i][j] = QV[i + (jd>=1026)] . R[(jd+1023) mod 2049], jd = j-i; 0 at jd==1025.
//   jd spans 127 consecutive values per tile -> one 128-wide R window per band.
//   band GEMM G[r][c'] = QVrows . Rwin (64x128, K=64); gather idx = col - r + 63.
__global__ __launch_bounds__(256,2) void flash_attn4(
    const unsigned short* __restrict__ QU, const unsigned short* __restrict__ QV,
    const unsigned short* __restrict__ qkvo, const unsigned short* __restrict__ VT,
    const unsigned short* __restrict__ relo, unsigned short* __restrict__ AV)
{
  __shared__ __align__(16) unsigned short qu_s[64*72];
  __shared__ __align__(16) unsigned short qv_s[65*72];
  __shared__ __align__(16) unsigned short k_s [64*72];
  __shared__ __align__(16) unsigned short vT_s[64*72];
  __shared__ __align__(16) unsigned short r_s [128*64];  // XOR 16B slots
  __shared__ __align__(16) unsigned short g_s [64*128];
  __shared__ __align__(16) unsigned short p_s [64*72];
  __shared__ float l_s[64];

  const int tid = threadIdx.x, lane = tid&63, wave = tid>>6;
  const int bh = blockIdx.x, b = bh>>4, h = bh&15;
  const int i0 = blockIdx.y*64;
  const int qr = wave>>1, qc = wave&1;
  const unsigned short* QUb = QU + (size_t)bh*S_*DH_;
  const unsigned short* QVb = QV + (size_t)bh*S_*DH_;
  const unsigned short* Kg  = qkvo + (size_t)b*3072 + 1024 + h*64;   // + t*12288
  const unsigned short* VTb = VT + (size_t)bh*64*T_;
  const unsigned short* Rg  = relo + (size_t)b*1024 + h*64;          // + t*4096

  // stage QU rows i0..i0+63 and QV rows i0..i0+64 (65 rows; +64 clamped)
  for (int c=0;c<2;c++){
    int ch = c*256+tid; int row = ch>>3, off=(ch&7)*8;
    *(uint4*)&qu_s[row*72+off] = *(const uint4*)&QUb[(size_t)(i0+row)*64 + off];
    *(uint4*)&qv_s[row*72+off] = *(const uint4*)&QVb[(size_t)(i0+row)*64 + off];
  }
  if (tid < 8) {
    int rr = i0 + 64; if (rr > S_-1) rr = S_-1;
    *(uint4*)&qv_s[64*72 + tid*8] = *(const uint4*)&QVb[(size_t)rr*64 + tid*8];
  }

  f32x16 acc_o;
  for (int e=0;e<16;e++) acc_o[e]=0.f;
  float lreg = 0.f;

  const int col = qc*32 + (lane&31);
  int rowl[16];
  for (int e=0;e<16;e++) rowl[e] = qr*32 + (e&3) + 8*(e>>2) + 4*(lane>>5);

  for (int j0 = 0; j0 < T_; j0 += 64) {
    const int jdmax = j0 + 63 - i0;
    const int jdmin = j0 - 63 - i0;
    const int cls = (jdmax <= 1024) ? 0 : ((jdmin >= 1026) ? 2 : 1);
    const int wb = (cls == 2) ? (j0 - i0 - 1089) : (j0 - i0 + 960);
    const int ashift = (cls == 2) ? 1 : 0;

    // stage K, VT (padded-72), R window (XOR slots)
    for (int c=0;c<2;c++){
      int ch = c*256+tid; int row = ch>>3, off=(ch&7)*8;
      *(uint4*)&k_s[row*72+off]  = *(const uint4*)&Kg[(size_t)(j0+row)*12288 + off];
      *(uint4*)&vT_s[row*72+off] = *(const uint4*)&VTb[(size_t)row*T_ + j0 + off];
    }
    for (int c=0;c<4;c++){
      int ch = c*256+tid; int rr = ch>>3, off = ch&7;
      int t = wb + rr; t = t < 0 ? 0 : (t > T_-1 ? T_-1 : t);
      *(uint4*)&r_s[rr*64 + ((off ^ (rr&7))<<3)] = *(const uint4*)&Rg[(size_t)t*4096 + off*8];
    }
    __syncthreads();

    // band GEMM: 2 quads per wave -> g_s
    for (int qi=0; qi<2; qi++){
      int qq = qc*2 + qi;
      f32x16 gacc;
      for (int e=0;e<16;e++) gacc[e]=0.f;
      for (int ks=0; ks<4; ks++){
        int koff = ks*16 + (lane>>5)*8, kb = ks*2 + (lane>>5);
        int ar = qr*32 + (lane&31) + ashift;
        int br = qq*32 + (lane&31);
        s16x8 a  = *(const s16x8*)&qv_s[ar*72 + koff];
        s16x8 bb = *(const s16x8*)&r_s[br*64 + ((kb ^ (br&7))<<3)];
        gacc = __builtin_amdgcn_mfma_f32_32x32x16_bf16(a, bb, gacc, 0,0,0);
      }
      for (int e=0;e<16;e++){
        int r = qr*32 + (e&3) + 8*(e>>2) + 4*(lane>>5);
        g_s[r*128 + qq*32 + (lane&31)] = f2b(gacc[e]);
      }
    }
    // AC quad
    f32x16 acc;
    for (int e=0;e<16;e++) acc[e]=0.f;
    for (int ks=0; ks<4; ks++){
      int koff = ks*16 + (lane>>5)*8;
      s16x8 a  = *(const s16x8*)&qu_s[(qr*32+(lane&31))*72 + koff];
      s16x8 bq = *(const s16x8*)&k_s[(qc*32+(lane&31))*72 + koff];
      acc = __builtin_amdgcn_mfma_f32_32x32x16_bf16(a, bq, acc, 0,0,0);
    }
    __syncthreads();

    // assembly phase A (all of cls 0/2; jd<=1025 part of cls 1)
    for (int e=0;e<16;e++){
      int r = rowl[e];
      int jd = j0 + col - (i0 + r);
      if (cls == 1 && jd >= 1026) continue;
      float bd = (jd == 1025) ? 0.f : b2f(g_s[r*128 + (col - r + 63)]);
      p_s[r*72 + col] = f2b(__expf((acc[e] + bd) * 0.125f));
    }
    if (cls == 1) {
      __syncthreads();                       // g_s / r_s consumed
      const int wb2 = j0 - i0 - 1089;
      for (int c=0;c<4;c++){
        int ch = c*256+tid; int rr = ch>>3, off = ch&7;
        int t = wb2 + rr; t = t < 0 ? 0 : (t > T_-1 ? T_-1 : t);
        *(uint4*)&r_s[rr*64 + ((off ^ (rr&7))<<3)] = *(const uint4*)&Rg[(size_t)t*4096 + off*8];
      }
      __syncthreads();
      for (int qi=0; qi<2; qi++){
        int qq = qc*2 + qi;
        f32x16 gacc;
        for (int e=0;e<16;e++) gacc[e]=0.f;
        for (int ks=0; ks<4; ks++){
          int koff = ks*16 + (lane>>5)*8, kb = ks*2 + (lane>>5);
          int ar = qr*32 + (lane&31) + 1;    // wrap band uses QV[i+1]
          int br = qq*32 + (lane&31);
          s16x8 a  = *(const s16x8*)&qv_s[ar*72 + koff];
          s16x8 bb = *(const s16x8*)&r_s[br*64 + ((kb ^ (br&7))<<3)];
          gacc = __builtin_amdgcn_mfma_f32_32x32x16_bf16(a, bb, gacc, 0,0,0);
        }
        for (int e=0;e<16;e++){
          int r = qr*32 + (e&3) + 8*(e>>2) + 4*(lane>>5);
          g_s[r*128 + qq*32 + (lane&31)] = f2b(gacc[e]);
        }
      }
      __syncthreads();
      for (int e=0;e<16;e++){
        int r = rowl[e];
        int jd = j0 + col - (i0 + r);
        if (jd < 1026) continue;
        float bd = b2f(g_s[r*128 + (col - r + 63)]);
        p_s[r*72 + col] = f2b(__expf((acc[e] + bd) * 0.125f));
      }
    }
    __syncthreads();

    // rowsum (4 threads per row)
    {
      int rr = tid>>2, cb = (tid&3)*16;
      uint4 x0 = *(const uint4*)&p_s[rr*72+cb];
      uint4 x1 = *(const uint4*)&p_s[rr*72+cb+8];
      unsigned vs[8] = {x0.x,x0.y,x0.z,x0.w,x1.x,x1.y,x1.z,x1.w};
      float s = 0.f;
      for (int e=0;e<8;e++) s += b2f((unsigned short)(vs[e]&0xffff)) + b2f((unsigned short)(vs[e]>>16));
      s += __shfl_xor(s, 1, 64);
      s += __shfl_xor(s, 2, 64);
      if ((tid&3)==0) lreg += s;
    }
    // PV quad
    for (int ks=0; ks<4; ks++){
      int koff = ks*16 + (lane>>5)*8;
      s16x8 a  = *(const s16x8*)&p_s[(qr*32+(lane&31))*72 + koff];
      s16x8 bv = *(const s16x8*)&vT_s[(qc*32+(lane&31))*72 + koff];
      acc_o = __builtin_amdgcn_mfma_f32_32x32x16_bf16(a, bv, acc_o, 0,0,0);
    }
    __syncthreads();
  }

  if ((tid&3)==0) l_s[tid>>2] = lreg;
  __syncthreads();
  for (int e=0;e<16;e++){
    float oo = acc_o[e] / l_s[rowl[e]];
    AV[ ((size_t)(i0+rowl[e])*B_ + b)*(H_*DH_) + h*DH_ + col ] = f2b(oo);
  }
}

// ---------------- LayerNorm ----------------
__global__ __launch_bounds__(256) void ln_kernel(const float* __restrict__ y,
    const float* __restrict__ g, const float* __restrict__ be, float* __restrict__ o)
{
  __shared__ float red[8];
  int row = blockIdx.x, tid = threadIdx.x;
  const float* yr = y + (size_t)row*DM_;
  float v[4];
  for (int e=0;e<4;e++) v[e] = yr[tid + 256*e];
  float s = v[0]+v[1]+v[2]+v[3];
  for (int off=32; off>0; off>>=1) s += __shfl_down(s, off, 64);
  if ((tid&63)==0) red[tid>>6] = s;
  __syncthreads();
  if (tid==0) red[4] = red[0]+red[1]+red[2]+red[3];
  __syncthreads();
  float mu = red[4] * (1.f/DM_);
  __syncthreads();
  float q = 0.f;
  for (int e=0;e<4;e++){ float d = v[e]-mu; q += d*d; }
  for (int off=32; off>0; off>>=1) q += __shfl_down(q, off, 64);
  if ((tid&63)==0) red[tid>>6] = q;
  __syncthreads();
  if (tid==0) red[4] = red[0]+red[1]+red[2]+red[3];
  __syncthreads();
  float rstd = rsqrtf(red[4]*(1.f/DM_) + 1e-5f);
  for (int e=0;e<4;e++){
    int c = tid + 256*e;
    o[(size_t)row*DM_ + c] = g[c]*(v[e]-mu)*rstd + be[c];
  }
}

// ---------------- launch ----------------
extern "C" void kernel_launch(void* const* d_in, const int* in_sizes, int n_in,
                              void* d_out, int out_size, void* d_ws, size_t ws_size,
                              hipStream_t stream)
{
  const float* x    = (const float*)d_in[0];
  const float* mem  = (const float*)d_in[1];
  const float* pos  = (const float*)d_in[2];
  const float* pbu  = (const float*)d_in[3];
  const float* pbv  = (const float*)d_in[4];
  const float* wqkv = (const float*)d_in[5];
  const float* wrel = (const float*)d_in[6];
  const float* wo   = (const float*)d_in[7];
  const float* gam  = (const float*)d_in[8];
  const float* bet  = (const float*)d_in[9];
  float* out = (float*)d_out;

  char* w = (char*)d_ws;
  unsigned short* qkvo  = (unsigned short*)(w + 0);          // 50,331,648
  unsigned short* relo  = (unsigned short*)(w + 50331648);   // 16,777,216
  unsigned short* wo16  = (unsigned short*)(w + 67108864);   //  2,097,152
  unsigned short* QUb   = (unsigned short*)(w + 69206016);   //  8,388,608
  unsigned short* QVb   = (unsigned short*)(w + 77594624);   //  8,388,608
  unsigned short* VT    = (unsigned short*)(w + 85983232);   // 16,777,216
  unsigned short* av16  = (unsigned short*)(w + 102760448);  //  8,388,608
  float*          yf    = (float*)(w + 111149056);           // 16,777,216
  unsigned short* c16   = (unsigned short*)(w + 127926272);  // 16,777,216
  unsigned short* pos16 = (unsigned short*)(w + 144703488);  // 16,777,216
  unsigned short* wq16  = (unsigned short*)(w + 161480704);  //  6,291,456
  unsigned short* wr16  = (unsigned short*)(w + 167772160);  //  2,097,152 -> total 169,869,312

  cast_cat<<<4096, 256, 0, stream>>>(mem, x, c16, 1048576, 524288);
  cast_cat<<<4096, 256, 0, stream>>>(pos, pos, pos16, 1048576, 1048576);
  cast_cat<<<1536, 256, 0, stream>>>(wqkv, wqkv, wq16, 393216, 393216);
  cast_cat<<< 512, 256, 0, stream>>>(wrel, wrel, wr16, 131072, 131072);
  cast_cat<<< 512, 256, 0, stream>>>(wo,   wo,   wo16, 131072, 131072);

  gemm_nt<<<dim3(24,64), 256, 0, stream>>>(c16,   wq16, (void*)qkvo, nullptr, 3072, 1024, 0);
  gemm_nt<<<dim3(8,64),  256, 0, stream>>>(pos16, wr16, (void*)relo, nullptr, 1024, 1024, 0);

  scatter_quv<<<2048, 256, 0, stream>>>(qkvo, pbu, pbv, QUb, QVb);
  scatter_vt<<<dim3(64,32), 256, 0, stream>>>(qkvo, VT);

  flash_attn4<<<dim3(64,16), 256, 0, stream>>>(QUb, QVb, qkvo, VT, relo, av16);

  gemm_nt<<<dim3(8,32), 256, 0, stream>>>(av16, wo16, (void*)yf, x, 1024, 1024, 1);
  ln_kernel<<<4096, 256, 0, stream>>>(yf, gam, bet, out);
}